// Round 6
// baseline (105.355 us; speedup 1.0000x reference)
//
#include <hip/hip_runtime.h>

#define N_NODES 100000
#define N_EDGES 1600000
#define HIDDEN 256

#define BSH 7                    // bucket = dst >> 7
#define BNODES 128               // nodes per bucket
#define NB 782                   // ceil(N_NODES / 128)
#define CAP 2560                 // record slots per bucket (mean 2046, sigma ~45)
#define NPB 512                  // place blocks
#define EPB 3125                 // edges per place block (512*3125 = 1.6M exact)
#define EPT 13                   // ceil(EPB / 256) edges per thread
#define GSTR 16                  // gcur padded stride (64B per counter)
#define ZNPW 8                   // z: nodes per wave
#define ZNPB 32                  // z: nodes per block (4 waves)
#define NZB 3125                 // 3125*32 = 100000 exact

// record: uint2 { src(17b) | dstloc(7b)<<17 , float_bits(w) }

// ---- K0: fold W12 = W1@W2, cvec = b1@W2 + b2, clear padded gcur ----
__global__ __launch_bounds__(256) void k_init(
        const float* __restrict__ W1, const float* __restrict__ b1,
        const float* __restrict__ W2, const float* __restrict__ b2,
        float* __restrict__ W12, float* __restrict__ cvec, int* __restrict__ gcur) {
    if (blockIdx.x == 0) {
        int h = threadIdx.x;
        const float4* w1r = (const float4*)(W1 + (size_t)h * 128);
        float a0 = 0.f, a1 = 0.f;
#pragma unroll 8
        for (int k4 = 0; k4 < 32; ++k4) {
            float4 v = w1r[k4];
            a0 += v.x * W2[8 * k4 + 0]; a1 += v.x * W2[8 * k4 + 1];
            a0 += v.y * W2[8 * k4 + 2]; a1 += v.y * W2[8 * k4 + 3];
            a0 += v.z * W2[8 * k4 + 4]; a1 += v.z * W2[8 * k4 + 5];
            a0 += v.w * W2[8 * k4 + 6]; a1 += v.w * W2[8 * k4 + 7];
        }
        W12[2 * h] = a0; W12[2 * h + 1] = a1;
        if (h < 2) {
            float acc = b2[h];
            for (int k = 0; k < 128; ++k) acc += b1[k] * W2[2 * k + h];
            cvec[h] = acc;
        }
    } else {
        int i = (blockIdx.x - 1) * 256 + threadIdx.x;
        if (i < NB * GSTR) gcur[i] = 0;
    }
}

// ---- KA: blocks < NPB place records; remaining 3125 blocks compute z = x@W12 ----
__global__ __launch_bounds__(256) void k_main(
        const float* __restrict__ x, const int* __restrict__ ei,
        const float* __restrict__ ew, const float* __restrict__ W12,
        int* __restrict__ gcur, uint2* __restrict__ rec, float* __restrict__ z) {
    __shared__ struct { int hist[NB]; int cursor[NB]; } sm;   // 6256 B
    const int tid = threadIdx.x, bid = blockIdx.x;
    if (bid < NPB) {
        // -------- preload this thread's edges (one global burst, overlapped) ----
        const int e0 = bid * EPB, e1 = e0 + EPB;
        int dv[EPT]; int sv[EPT]; float wv[EPT];
#pragma unroll
        for (int k = 0; k < EPT; ++k) {
            int e = e0 + tid + k * 256;
            if (e < e1) {
                dv[k] = ei[N_EDGES + e];
                sv[k] = ei[e];
                wv[k] = ew[e];
            } else dv[k] = -1;
        }
        for (int i = tid; i < NB; i += 256) sm.hist[i] = 0;
        __syncthreads();
        // -------- hist (non-returning LDS atomics, no chain) --------
#pragma unroll
        for (int k = 0; k < EPT; ++k)
            if (dv[k] >= 0) atomicAdd(&sm.hist[((unsigned)dv[k]) >> BSH], 1);
        __syncthreads();
        // -------- chunk reservation on padded global counters --------
        for (int i = tid; i < NB; i += 256) {
            int c = sm.hist[i];
            int pos = c ? atomicAdd(&gcur[i * GSTR], c) : 0;
            sm.cursor[i] = i * CAP + pos;
        }
        __syncthreads();
        // -------- scatter records (LDS cursor atomic -> 8B store) --------
#pragma unroll
        for (int k = 0; k < EPT; ++k) {
            if (dv[k] >= 0) {
                int d = dv[k];
                int bk = ((unsigned)d) >> BSH;
                int p = atomicAdd(&sm.cursor[bk], 1);
                if (p < (bk + 1) * CAP)   // ~11-sigma margin, never hit
                    rec[p] = make_uint2(
                        (unsigned)sv[k] | ((unsigned)(d & (BNODES - 1)) << 17),
                        __float_as_uint(wv[k]));
            }
        }
    } else {
        const int lane = tid & 63;
        const float2 w0 = ((const float2*)W12)[lane * 4 + 0];
        const float2 w1 = ((const float2*)W12)[lane * 4 + 1];
        const float2 w2 = ((const float2*)W12)[lane * 4 + 2];
        const float2 w3 = ((const float2*)W12)[lane * 4 + 3];
        const int n0 = (bid - NPB) * ZNPB + (tid >> 6) * ZNPW;   // exact cover
#pragma unroll 4
        for (int k = 0; k < ZNPW; ++k) {
            const int node = n0 + k;
            float4 xv = *(const float4*)(x + (size_t)node * HIDDEN + lane * 4);
            float a0 = xv.x * w0.x + xv.y * w1.x + xv.z * w2.x + xv.w * w3.x;
            float a1 = xv.x * w0.y + xv.y * w1.y + xv.z * w2.y + xv.w * w3.y;
#pragma unroll
            for (int m = 32; m >= 1; m >>= 1) {
                a0 += __shfl_xor(a0, m, 64);
                a1 += __shfl_xor(a1, m, 64);
            }
            if (lane == 0) ((float2*)z)[node] = make_float2(a0, a1);
        }
    }
}

// ---- KB: deg per bucket -> dinv; premultiply zn = dinv * z ----
__global__ __launch_bounds__(256) void k_deg(
        const uint2* __restrict__ rec, const int* __restrict__ gcur,
        const float* __restrict__ z, float* __restrict__ dinv,
        float2* __restrict__ zn) {
    __shared__ float acc[BNODES];
    const int tid = threadIdx.x, b = blockIdx.x;
    for (int i = tid; i < BNODES; i += 256) acc[i] = 1.0f;   // self-loop w=1
    __syncthreads();
    const int n = min(gcur[b * GSTR], CAP);
    const uint2* r = rec + (size_t)b * CAP;
    int i = tid * 2;
    for (; i + 1 < n; i += 512) {
        uint4 q = *(const uint4*)(r + i);
        atomicAdd(&acc[q.x >> 17], __uint_as_float(q.y));
        atomicAdd(&acc[q.z >> 17], __uint_as_float(q.w));
    }
    if (i < n) {
        uint2 q = r[i];
        atomicAdd(&acc[q.x >> 17], __uint_as_float(q.y));
    }
    __syncthreads();
    for (int i2 = tid; i2 < BNODES; i2 += 256) {
        int node = b * BNODES + i2;
        if (node < N_NODES) {
            float di = rsqrtf(acc[i2]);              // deg >= 1 always
            dinv[node] = di;
            float2 zv = ((const float2*)z)[node];
            zn[node] = make_float2(di * zv.x, di * zv.y);
        }
    }
}

// ---- KC: gather zn[src]*w into LDS; flush fuses self-loop + bias ----
__global__ __launch_bounds__(256) void k_gather(
        const uint2* __restrict__ rec, const int* __restrict__ gcur,
        const float* __restrict__ dinv, const float2* __restrict__ zn,
        const float* __restrict__ cvec, float2* __restrict__ out) {
    __shared__ float ax[BNODES], ay[BNODES];
    const int tid = threadIdx.x, b = blockIdx.x;
    for (int i = tid; i < BNODES; i += 256) { ax[i] = 0.f; ay[i] = 0.f; }
    __syncthreads();
    const int n = min(gcur[b * GSTR], CAP);
    const uint2* r = rec + (size_t)b * CAP;
    int i = tid * 2;
    for (; i + 1 < n; i += 512) {
        uint4 q = *(const uint4*)(r + i);
        {
            float w = __uint_as_float(q.y);
            float2 s = zn[q.x & 0x1FFFFu];
            int dl = (int)(q.x >> 17);
            atomicAdd(&ax[dl], w * s.x);
            atomicAdd(&ay[dl], w * s.y);
        }
        {
            float w = __uint_as_float(q.w);
            float2 s = zn[q.z & 0x1FFFFu];
            int dl = (int)(q.z >> 17);
            atomicAdd(&ax[dl], w * s.x);
            atomicAdd(&ay[dl], w * s.y);
        }
    }
    if (i < n) {
        uint2 q = r[i];
        float w = __uint_as_float(q.y);
        float2 s = zn[q.x & 0x1FFFFu];
        int dl = (int)(q.x >> 17);
        atomicAdd(&ax[dl], w * s.x);
        atomicAdd(&ay[dl], w * s.y);
    }
    __syncthreads();
    const float c0 = cvec[0], c1 = cvec[1];
    for (int i2 = tid; i2 < BNODES; i2 += 256) {
        int node = b * BNODES + i2;
        if (node < N_NODES) {
            float di = dinv[node];
            float2 s = zn[node];
            out[node] = make_float2(di * ax[i2] + di * s.x + c0,
                                    di * ay[i2] + di * s.y + c1);
        }
    }
}

extern "C" void kernel_launch(void* const* d_in, const int* in_sizes, int n_in,
                              void* d_out, int out_size, void* d_ws, size_t ws_size,
                              hipStream_t stream) {
    const float* x  = (const float*)d_in[0];
    const int*   ei = (const int*)d_in[1];
    const float* ew = (const float*)d_in[2];
    const float* W1 = (const float*)d_in[3];
    const float* b1 = (const float*)d_in[4];
    const float* W2 = (const float*)d_in[5];
    const float* b2 = (const float*)d_in[6];
    float2* out = (float2*)d_out;

    char* ws = (char*)d_ws;
    uint2*  rec  = (uint2*)ws;           size_t off = (size_t)NB * CAP * 8;  // 16,015,360
    int*    gcur = (int*)(ws + off);     off += (size_t)NB * GSTR * 4;       // 50,048
    float*  dinv = (float*)(ws + off);   off += (size_t)N_NODES * 4;
    float*  z    = (float*)(ws + off);   off += (size_t)N_NODES * 8;
    float2* zn   = (float2*)(ws + off);  off += (size_t)N_NODES * 8;
    float*  W12  = (float*)(ws + off);   off += HIDDEN * 2 * 4;
    float*  cvec = (float*)(ws + off);   off += 16;

    k_init  <<<1 + (NB * GSTR + 255) / 256, 256, 0, stream>>>(W1, b1, W2, b2, W12, cvec, gcur);
    k_main  <<<NPB + NZB, 256, 0, stream>>>(x, ei, ew, W12, gcur, rec, z);
    k_deg   <<<NB, 256, 0, stream>>>(rec, gcur, z, dinv, zn);
    k_gather<<<NB, 256, 0, stream>>>(rec, gcur, dinv, zn, cvec, out);
}

// Round 7
// 88.060 us; speedup vs baseline: 1.1964x; 1.1964x over previous
//
#include <hip/hip_runtime.h>

#define N_NODES 100000
#define N_EDGES 1600000
#define HIDDEN 256

#define BSH 7                    // bucket = dst >> 7
#define BNODES 128               // nodes per bucket
#define NB 782                   // ceil(100000 / 128)
#define NPB 256                  // place blocks
#define EPB 6250                 // edges per place block (256*6250 = 1.6M exact)
#define SLOTS 32                 // slots per (bucket, place-block): mean 8, P(ovf)~4e-11
#define NZB 25000                // z blocks, 4 nodes each (1 node/wave) = 100000 exact

// rec layout: [bucket][pblock][slot], 8B records {src|dstloc<<17, w}
// cnt layout: [pblock][bucket]

// ---- K0: fold W12 = W1@W2, cvec = b1@W2 + b2; clear cnt ----
__global__ __launch_bounds__(256) void k_init(
        const float* __restrict__ W1, const float* __restrict__ b1,
        const float* __restrict__ W2, const float* __restrict__ b2,
        float* __restrict__ W12, float* __restrict__ cvec, int* __restrict__ cnt) {
    if (blockIdx.x == 0) {
        int h = threadIdx.x;
        const float4* w1r = (const float4*)(W1 + (size_t)h * 128);
        float a0 = 0.f, a1 = 0.f;
#pragma unroll 8
        for (int k4 = 0; k4 < 32; ++k4) {
            float4 v = w1r[k4];
            a0 += v.x * W2[8 * k4 + 0]; a1 += v.x * W2[8 * k4 + 1];
            a0 += v.y * W2[8 * k4 + 2]; a1 += v.y * W2[8 * k4 + 3];
            a0 += v.z * W2[8 * k4 + 4]; a1 += v.z * W2[8 * k4 + 5];
            a0 += v.w * W2[8 * k4 + 6]; a1 += v.w * W2[8 * k4 + 7];
        }
        W12[2 * h] = a0; W12[2 * h + 1] = a1;
        if (h < 2) {
            float acc = b2[h];
            for (int k = 0; k < 128; ++k) acc += b1[k] * W2[2 * k + h];
            cvec[h] = acc;
        }
    } else {
        int i = (blockIdx.x - 1) * 256 + threadIdx.x;
        if (i < NPB * NB) cnt[i] = 0;
    }
}

// ---- KA: blocks < NPB: single-pass place (no global atomics, no hist).
//          blocks >= NPB: z = x@W12, one node per wave. ----
__global__ __launch_bounds__(256) void k_main(
        const float* __restrict__ x, const int* __restrict__ ei,
        const float* __restrict__ ew, const float* __restrict__ W12,
        int* __restrict__ cnt, uint2* __restrict__ rec, float* __restrict__ z) {
    __shared__ int cursor[NB];
    const int tid = threadIdx.x, bid = blockIdx.x;
    if (bid < NPB) {
        for (int i = tid; i < NB; i += 256) cursor[i] = 0;
        __syncthreads();
        const int e0 = bid * EPB, e1 = e0 + EPB;
        for (int e = e0 + tid; e < e1; e += 256) {
            int d = ei[N_EDGES + e];
            int s = ei[e];
            float wv = ew[e];
            int bk = ((unsigned)d) >> BSH;
            int pos = atomicAdd(&cursor[bk], 1);      // block-local LDS cursor
            if (pos < SLOTS)                          // ~4e-11 per pair, see header
                rec[((size_t)bk * NPB + bid) * SLOTS + pos] =
                    make_uint2((unsigned)s | ((unsigned)(d & (BNODES - 1)) << 17),
                               __float_as_uint(wv));
        }
        __syncthreads();
        for (int i = tid; i < NB; i += 256)
            cnt[bid * NB + i] = min(cursor[i], SLOTS);
    } else {
        const int lane = tid & 63;
        const float2 w0 = ((const float2*)W12)[lane * 4 + 0];
        const float2 w1 = ((const float2*)W12)[lane * 4 + 1];
        const float2 w2 = ((const float2*)W12)[lane * 4 + 2];
        const float2 w3 = ((const float2*)W12)[lane * 4 + 3];
        const int node = (bid - NPB) * 4 + (tid >> 6);      // exact cover, no guard
        float4 xv = *(const float4*)(x + (size_t)node * HIDDEN + lane * 4);
        float a0 = xv.x * w0.x + xv.y * w1.x + xv.z * w2.x + xv.w * w3.x;
        float a1 = xv.x * w0.y + xv.y * w1.y + xv.z * w2.y + xv.w * w3.y;
#pragma unroll
        for (int m = 32; m >= 1; m >>= 1) {
            a0 += __shfl_xor(a0, m, 64);
            a1 += __shfl_xor(a1, m, 64);
        }
        if (lane == 0) ((float2*)z)[node] = make_float2(a0, a1);
    }
}

// ---- KB: deg per bucket over sub-chunks -> dinv; premultiply zn = dinv*z ----
__global__ __launch_bounds__(256) void k_deg(
        const uint2* __restrict__ rec, const int* __restrict__ cnt,
        const float* __restrict__ z, float* __restrict__ dinv,
        float2* __restrict__ zn) {
    __shared__ float acc[BNODES];
    __shared__ int csh[NPB];
    const int tid = threadIdx.x, b = blockIdx.x;
    for (int i = tid; i < BNODES; i += 256) acc[i] = 1.0f;   // self-loop w=1
    csh[tid] = cnt[tid * NB + b];
    __syncthreads();
    const uint2* r = rec + (size_t)b * NPB * SLOTS;
    for (int idx = tid; idx < NPB * SLOTS; idx += 256) {
        int j = idx >> 5, s2 = idx & (SLOTS - 1);
        if (s2 < csh[j]) {
            uint2 q = r[idx];
            atomicAdd(&acc[q.x >> 17], __uint_as_float(q.y));
        }
    }
    __syncthreads();
    for (int i2 = tid; i2 < BNODES; i2 += 256) {
        int node = b * BNODES + i2;
        if (node < N_NODES) {
            float di = rsqrtf(acc[i2]);               // deg >= 1 always
            dinv[node] = di;
            float2 zv = ((const float2*)z)[node];
            zn[node] = make_float2(di * zv.x, di * zv.y);
        }
    }
}

// ---- KC: gather zn[src]*w per bucket; flush fuses self-loop + bias ----
__global__ __launch_bounds__(256) void k_gather(
        const uint2* __restrict__ rec, const int* __restrict__ cnt,
        const float* __restrict__ dinv, const float2* __restrict__ zn,
        const float* __restrict__ cvec, float2* __restrict__ out) {
    __shared__ float ax[BNODES], ay[BNODES];
    __shared__ int csh[NPB];
    const int tid = threadIdx.x, b = blockIdx.x;
    for (int i = tid; i < BNODES; i += 256) { ax[i] = 0.f; ay[i] = 0.f; }
    csh[tid] = cnt[tid * NB + b];
    __syncthreads();
    const uint2* r = rec + (size_t)b * NPB * SLOTS;
    for (int idx = tid; idx < NPB * SLOTS; idx += 256) {
        int j = idx >> 5, s2 = idx & (SLOTS - 1);
        if (s2 < csh[j]) {
            uint2 q = r[idx];
            float w = __uint_as_float(q.y);
            float2 s = zn[q.x & 0x1FFFFu];
            int dl = (int)(q.x >> 17);
            atomicAdd(&ax[dl], w * s.x);
            atomicAdd(&ay[dl], w * s.y);
        }
    }
    __syncthreads();
    const float c0 = cvec[0], c1 = cvec[1];
    for (int i2 = tid; i2 < BNODES; i2 += 256) {
        int node = b * BNODES + i2;
        if (node < N_NODES) {
            float di = dinv[node];
            float2 s = zn[node];
            out[node] = make_float2(di * ax[i2] + di * s.x + c0,
                                    di * ay[i2] + di * s.y + c1);
        }
    }
}

extern "C" void kernel_launch(void* const* d_in, const int* in_sizes, int n_in,
                              void* d_out, int out_size, void* d_ws, size_t ws_size,
                              hipStream_t stream) {
    const float* x  = (const float*)d_in[0];
    const int*   ei = (const int*)d_in[1];
    const float* ew = (const float*)d_in[2];
    const float* W1 = (const float*)d_in[3];
    const float* b1 = (const float*)d_in[4];
    const float* W2 = (const float*)d_in[5];
    const float* b2 = (const float*)d_in[6];
    float2* out = (float2*)d_out;

    char* ws = (char*)d_ws;
    uint2*  rec  = (uint2*)ws;           size_t off = (size_t)NB * NPB * SLOTS * 8;  // 51,249,152
    int*    cnt  = (int*)(ws + off);     off += (size_t)NPB * NB * 4;                // 800,768
    float*  dinv = (float*)(ws + off);   off += (size_t)N_NODES * 4;
    float*  z    = (float*)(ws + off);   off += (size_t)N_NODES * 8;
    float2* zn   = (float2*)(ws + off);  off += (size_t)N_NODES * 8;
    float*  W12  = (float*)(ws + off);   off += HIDDEN * 2 * 4;
    float*  cvec = (float*)(ws + off);   off += 16;

    k_init  <<<1 + (NPB * NB + 255) / 256, 256, 0, stream>>>(W1, b1, W2, b2, W12, cvec, cnt);
    k_main  <<<NPB + NZB, 256, 0, stream>>>(x, ei, ew, W12, cnt, rec, z);
    k_deg   <<<NB, 256, 0, stream>>>(rec, cnt, z, dinv, zn);
    k_gather<<<NB, 256, 0, stream>>>(rec, cnt, dinv, zn, cvec, out);
}

// Round 8
// 85.758 us; speedup vs baseline: 1.2285x; 1.0268x over previous
//
#include <hip/hip_runtime.h>

#define N_NODES 100000
#define N_EDGES 1600000
#define HIDDEN 256

#define BSH 7                    // bucket = dst >> 7
#define BNODES 128               // nodes per bucket
#define NB 782                   // ceil(100000 / 128)
#define NPB 256                  // place blocks
#define EPB 6250                 // edges per place block (256*6250 = 1.6M exact)
#define SLOTS 32                 // slots per (bucket, place-block): mean 8, P(ovf)~4e-11
#define NZB 25000                // z blocks, 4 nodes each (1 node/wave) = 100000 exact

// rec layout: [bucket][pblock][slot], 8B records {src|dstloc<<17, w}
// cnt layout: [pblock][bucket]

// ---- K0: fold W12 = W1@W2, cvec = b1@W2 + b2; clear cnt ----
__global__ __launch_bounds__(256) void k_init(
        const float* __restrict__ W1, const float* __restrict__ b1,
        const float* __restrict__ W2, const float* __restrict__ b2,
        float* __restrict__ W12, float* __restrict__ cvec, int* __restrict__ cnt) {
    if (blockIdx.x == 0) {
        int h = threadIdx.x;
        const float4* w1r = (const float4*)(W1 + (size_t)h * 128);
        float a0 = 0.f, a1 = 0.f;
#pragma unroll 8
        for (int k4 = 0; k4 < 32; ++k4) {
            float4 v = w1r[k4];
            a0 += v.x * W2[8 * k4 + 0]; a1 += v.x * W2[8 * k4 + 1];
            a0 += v.y * W2[8 * k4 + 2]; a1 += v.y * W2[8 * k4 + 3];
            a0 += v.z * W2[8 * k4 + 4]; a1 += v.z * W2[8 * k4 + 5];
            a0 += v.w * W2[8 * k4 + 6]; a1 += v.w * W2[8 * k4 + 7];
        }
        W12[2 * h] = a0; W12[2 * h + 1] = a1;
        if (h < 2) {
            float acc = b2[h];
            for (int k = 0; k < 128; ++k) acc += b1[k] * W2[2 * k + h];
            cvec[h] = acc;
        }
    } else {
        int i = (blockIdx.x - 1) * 256 + threadIdx.x;
        if (i < NPB * NB) cnt[i] = 0;
    }
}

// ---- KZ: z = x@W12, one node per wave, 4 waves/block, exact cover ----
__global__ __launch_bounds__(256) void k_z(
        const float* __restrict__ x, const float* __restrict__ W12,
        float* __restrict__ z) {
    const int tid = threadIdx.x;
    const int lane = tid & 63;
    const float2 w0 = ((const float2*)W12)[lane * 4 + 0];
    const float2 w1 = ((const float2*)W12)[lane * 4 + 1];
    const float2 w2 = ((const float2*)W12)[lane * 4 + 2];
    const float2 w3 = ((const float2*)W12)[lane * 4 + 3];
    const int node = blockIdx.x * 4 + (tid >> 6);
    float4 xv = *(const float4*)(x + (size_t)node * HIDDEN + lane * 4);
    float a0 = xv.x * w0.x + xv.y * w1.x + xv.z * w2.x + xv.w * w3.x;
    float a1 = xv.x * w0.y + xv.y * w1.y + xv.z * w2.y + xv.w * w3.y;
#pragma unroll
    for (int m = 32; m >= 1; m >>= 1) {
        a0 += __shfl_xor(a0, m, 64);
        a1 += __shfl_xor(a1, m, 64);
    }
    if (lane == 0) ((float2*)z)[node] = make_float2(a0, a1);
}

// ---- KP: single-pass place, 1024 threads/block (16 waves/CU of TLP) ----
__global__ __launch_bounds__(1024) void k_place(
        const int* __restrict__ ei, const float* __restrict__ ew,
        int* __restrict__ cnt, uint2* __restrict__ rec) {
    __shared__ int cursor[NB];
    const int tid = threadIdx.x, bid = blockIdx.x;
    for (int i = tid; i < NB; i += 1024) cursor[i] = 0;
    __syncthreads();
    const int e0 = bid * EPB, e1 = e0 + EPB;
    for (int e = e0 + tid; e < e1; e += 1024) {
        int d = ei[N_EDGES + e];
        int s = ei[e];
        float wv = ew[e];
        int bk = ((unsigned)d) >> BSH;
        int pos = atomicAdd(&cursor[bk], 1);          // block-local LDS cursor
        if (pos < SLOTS)                              // ~4e-11 per pair
            rec[((size_t)bk * NPB + bid) * SLOTS + pos] =
                make_uint2((unsigned)s | ((unsigned)(d & (BNODES - 1)) << 17),
                           __float_as_uint(wv));
    }
    __syncthreads();
    for (int i = tid; i < NB; i += 1024)
        cnt[bid * NB + i] = min(cursor[i], SLOTS);
}

// ---- KB: deg per bucket over sub-chunks -> dinv; premultiply zn = dinv*z ----
__global__ __launch_bounds__(256) void k_deg(
        const uint2* __restrict__ rec, const int* __restrict__ cnt,
        const float* __restrict__ z, float* __restrict__ dinv,
        float2* __restrict__ zn) {
    __shared__ float acc[BNODES];
    __shared__ int csh[NPB];
    const int tid = threadIdx.x, b = blockIdx.x;
    for (int i = tid; i < BNODES; i += 256) acc[i] = 1.0f;   // self-loop w=1
    csh[tid] = cnt[tid * NB + b];
    __syncthreads();
    const uint2* r = rec + (size_t)b * NPB * SLOTS;
    for (int idx = tid; idx < NPB * SLOTS; idx += 256) {
        int j = idx >> 5, s2 = idx & (SLOTS - 1);
        if (s2 < csh[j]) {
            uint2 q = r[idx];
            atomicAdd(&acc[q.x >> 17], __uint_as_float(q.y));
        }
    }
    __syncthreads();
    for (int i2 = tid; i2 < BNODES; i2 += 256) {
        int node = b * BNODES + i2;
        if (node < N_NODES) {
            float di = rsqrtf(acc[i2]);               // deg >= 1 always
            dinv[node] = di;
            float2 zv = ((const float2*)z)[node];
            zn[node] = make_float2(di * zv.x, di * zv.y);
        }
    }
}

// ---- KC: gather zn[src]*w per bucket; flush fuses self-loop + bias ----
__global__ __launch_bounds__(256) void k_gather(
        const uint2* __restrict__ rec, const int* __restrict__ cnt,
        const float* __restrict__ dinv, const float2* __restrict__ zn,
        const float* __restrict__ cvec, float2* __restrict__ out) {
    __shared__ float ax[BNODES], ay[BNODES];
    __shared__ int csh[NPB];
    const int tid = threadIdx.x, b = blockIdx.x;
    for (int i = tid; i < BNODES; i += 256) { ax[i] = 0.f; ay[i] = 0.f; }
    csh[tid] = cnt[tid * NB + b];
    __syncthreads();
    const uint2* r = rec + (size_t)b * NPB * SLOTS;
    for (int idx = tid; idx < NPB * SLOTS; idx += 256) {
        int j = idx >> 5, s2 = idx & (SLOTS - 1);
        if (s2 < csh[j]) {
            uint2 q = r[idx];
            float w = __uint_as_float(q.y);
            float2 s = zn[q.x & 0x1FFFFu];
            int dl = (int)(q.x >> 17);
            atomicAdd(&ax[dl], w * s.x);
            atomicAdd(&ay[dl], w * s.y);
        }
    }
    __syncthreads();
    const float c0 = cvec[0], c1 = cvec[1];
    for (int i2 = tid; i2 < BNODES; i2 += 256) {
        int node = b * BNODES + i2;
        if (node < N_NODES) {
            float di = dinv[node];
            float2 s = zn[node];
            out[node] = make_float2(di * ax[i2] + di * s.x + c0,
                                    di * ay[i2] + di * s.y + c1);
        }
    }
}

extern "C" void kernel_launch(void* const* d_in, const int* in_sizes, int n_in,
                              void* d_out, int out_size, void* d_ws, size_t ws_size,
                              hipStream_t stream) {
    const float* x  = (const float*)d_in[0];
    const int*   ei = (const int*)d_in[1];
    const float* ew = (const float*)d_in[2];
    const float* W1 = (const float*)d_in[3];
    const float* b1 = (const float*)d_in[4];
    const float* W2 = (const float*)d_in[5];
    const float* b2 = (const float*)d_in[6];
    float2* out = (float2*)d_out;

    char* ws = (char*)d_ws;
    uint2*  rec  = (uint2*)ws;           size_t off = (size_t)NB * NPB * SLOTS * 8;  // 51,249,152
    int*    cnt  = (int*)(ws + off);     off += (size_t)NPB * NB * 4;                // 800,768
    float*  dinv = (float*)(ws + off);   off += (size_t)N_NODES * 4;
    float*  z    = (float*)(ws + off);   off += (size_t)N_NODES * 8;
    float2* zn   = (float2*)(ws + off);  off += (size_t)N_NODES * 8;
    float*  W12  = (float*)(ws + off);   off += HIDDEN * 2 * 4;
    float*  cvec = (float*)(ws + off);   off += 16;

    k_init  <<<1 + (NPB * NB + 255) / 256, 256, 0, stream>>>(W1, b1, W2, b2, W12, cvec, cnt);
    k_z     <<<NZB, 256, 0, stream>>>(x, W12, z);
    k_place <<<NPB, 1024, 0, stream>>>(ei, ew, cnt, rec);
    k_deg   <<<NB, 256, 0, stream>>>(rec, cnt, z, dinv, zn);
    k_gather<<<NB, 256, 0, stream>>>(rec, cnt, dinv, zn, cvec, out);
}